// Round 7
// baseline (74.037 us; speedup 1.0000x reference)
//
#include <hip/hip_runtime.h>

#define NC 65
#define NCELL 274625
#define NE 19
#define NF 8
#define LSTR 11    // per-cell LDS stride: [0..7]=sdf corners, [8]=ins, [9]=ijk, [10] pad

// MT_TRI rows packed 4 bits per entry (0xF == -1), entry v at bits [4v,4v+4)
__constant__ unsigned MTP[16] = {
    0x00FFFFFFu, 0x00FFF210u, 0x00FFF430u, 0x00341421u,
    0x00FFF531u, 0x00350520u, 0x00450510u, 0x00FFF542u,
    0x00FFF542u, 0x00450510u, 0x00250530u, 0x00FFF531u,
    0x00241431u, 0x00FFF430u, 0x00FFF210u, 0x00FFFFFFu
};
// T2C rows packed 5 bits per entry: entry e at bits [5e,5e+5)
__constant__ unsigned T2CPc[6] = {
    0x0A418820u, 0x105388C1u, 0x16850926u,
    0x1CB68989u, 0x22E809ECu, 0x0919080Fu
};
// cell-edge endpoints (reference discovery order)
__device__ constexpr int EA[NE] = {0,0,0,1,1,3,0,2,2,0,2,6,0,4,4,0,4,5,1};
__device__ constexpr int EB[NE] = {1,3,7,3,7,7,2,3,7,6,6,7,4,6,7,5,5,7,5};
// Bit-packed (3 bits per edge); verified entry-by-entry (R3 errata fixed).
#define EAP 0x006C120C82419200ULL
#define EBP 0x017DBF4FB76BF7D9ULL
// Tets: corner0=0, corner3=7 for all tets; (c1 | c2<<3) at bits [6ti,6ti+6)
#define TETP 0x36C9B24D9ULL

typedef float float4u __attribute__((ext_vector_type(4), aligned(4)));

// one vert component from region-flat dword index P (= c*57 + e*3 + comp)
__device__ __forceinline__ float vertVal(const float* lds, int P) {
    const unsigned c    = (unsigned)P / 57u;
    const unsigned rem  = (unsigned)P - c * 57u;
    const unsigned e    = rem / 3u;
    const unsigned comp = rem - e * 3u;
    const float* Ld = lds + c * LSTR;
    const unsigned meta = __float_as_uint(Ld[9]);
    const unsigned a = (unsigned)(EAP >> (3u * e)) & 7u;
    const unsigned b = (unsigned)(EBP >> (3u * e)) & 7u;
    const float sa = Ld[a], sb = Ld[b];
    const bool cross = (sa < 0.0f) != (sb < 0.0f);
    const float t = cross ? sa / (sa - sb) : 0.0f;
    const float coord = (float)(int)((meta >> (7u * comp)) & 127u);
    const float pa = coord + (float)(int)((a >> comp) & 1u);
    const float pb = coord + (float)(int)((b >> comp) & 1u);
    const float v = cross ? pa + t * (pb - pa) : 0.0f;
    return (v - 1.0f) * (1.0f / 63.0f);
}

extern "C" __global__ void __launch_bounds__(256, 4)
diffmc_kernel(const float* __restrict__ sdf, const float* __restrict__ feat,
              float* __restrict__ oV, float* __restrict__ oF, float* __restrict__ oT)
{
    __shared__ float lds[256 * LSTR];
    const int tid = threadIdx.x;
    const int blockBase = blockIdx.x << 8;
    int vc = NCELL - blockBase;
    vc = vc > 256 ? 256 : vc;

    // ---------------- phase 0: per-cell corner sdf + meta ----------------
    if (tid < vc) {
        const int cell = blockBase + tid;
        const int k  = cell % NC;
        const int t_ = cell / NC;
        const int j  = t_ % NC;
        const int i  = t_ / NC;
        float cs[8];
#pragma unroll
        for (int c = 0; c < 8; ++c) {
            int x = i + (c & 1) - 1;
            int y = j + ((c >> 1) & 1) - 1;
            int z = k + ((c >> 2) & 1) - 1;
            bool inb = ((unsigned)x < 64u) & ((unsigned)y < 64u) & ((unsigned)z < 64u);
            cs[c] = inb ? sdf[(x * 64 + y) * 64 + z] : 1.0f;   // pad = iso + 1
        }
        unsigned ins = 0;
#pragma unroll
        for (int c = 0; c < 8; ++c) ins |= (cs[c] < 0.0f ? 1u : 0u) << c;
        float* Ld = lds + tid * LSTR;
#pragma unroll
        for (int c = 0; c < 8; ++c) Ld[c] = cs[c];
        Ld[8] = __uint_as_float(ins);
        Ld[9] = __uint_as_float((unsigned)i | ((unsigned)j << 7) | ((unsigned)k << 14));
    }
    __syncthreads();

    // ======== Phase V: dense float4 stores over vc*57 dwords (aligned) ======
    {
        const int nVd = vc * 57;
        const int nV4 = nVd >> 2;
        float* dV = oV + (size_t)blockBase * 57;
        float4u* dV4 = (float4u*)dV;
#pragma unroll 2
        for (int rr = 0; rr < 15; ++rr) {
            const int Q = tid + (rr << 8);
            if (Q >= nV4) break;
            float4u o;
#pragma unroll
            for (int u = 0; u < 4; ++u) o[u] = vertVal(lds, 4 * Q + u);
            dV4[Q] = o;
        }
        const int tP = (nV4 << 2) + tid;      // 0-3 leftover dwords (tail block)
        if (tP < nVd) dV[tP] = vertVal(lds, tP);
    }

    // ======== Phase F: dense float4 stores over vc*38 float4s ========
    {
        const int nF4 = vc * 38;
        float4u* dF4 = (float4u*)(oF + (size_t)blockBase * 152);
#pragma unroll 2
        for (int rr = 0; rr < 38; ++rr) {
            const int Q = tid + (rr << 8);
            if (Q >= nF4) break;
            const unsigned c    = (unsigned)Q / 38u;
            const unsigned rem  = (unsigned)Q - c * 38u;
            const unsigned e    = rem >> 1;
            const unsigned half = rem & 1u;
            const float* Ld = lds + c * LSTR;
            const unsigned meta = __float_as_uint(Ld[9]);
            const int ii = (int)(meta & 127u);
            const int jj = (int)((meta >> 7) & 127u);
            const int kk = (int)((meta >> 14) & 127u);
            const unsigned a = (unsigned)(EAP >> (3u * e)) & 7u;
            const unsigned b = (unsigned)(EBP >> (3u * e)) & 7u;
            const float sa = Ld[a], sb = Ld[b];
            const bool cross = (sa < 0.0f) != (sb < 0.0f);
            const float t = cross ? sa / (sa - sb) : 0.0f;

            const int xa = ii + (int)(a & 1u) - 1;
            const int ya = jj + (int)((a >> 1) & 1u) - 1;
            const int za = kk + (int)((a >> 2) & 1u) - 1;
            const int xb = ii + (int)(b & 1u) - 1;
            const int yb = jj + (int)((b >> 1) & 1u) - 1;
            const int zb = kk + (int)((b >> 2) & 1u) - 1;
            const bool iba = ((unsigned)xa < 64u) & ((unsigned)ya < 64u) & ((unsigned)za < 64u);
            const bool ibb = ((unsigned)xb < 64u) & ((unsigned)yb < 64u) & ((unsigned)zb < 64u);
            float4 fa = make_float4(0.f, 0.f, 0.f, 0.f), fb = fa;
            if (iba) fa = *(const float4*)(feat + (size_t)((xa * 64 + ya) * 64 + za) * NF + 4 * half);
            if (ibb) fb = *(const float4*)(feat + (size_t)((xb * 64 + yb) * 64 + zb) * NF + 4 * half);
            float4u o;
            o.x = cross ? fa.x + t * (fb.x - fa.x) : 0.0f;
            o.y = cross ? fa.y + t * (fb.y - fa.y) : 0.0f;
            o.z = cross ? fa.z + t * (fb.z - fa.z) : 0.0f;
            o.w = cross ? fa.w + t * (fb.w - fa.w) : 0.0f;
            dF4[Q] = o;
        }
    }

    // ======== Phase T: dense float4 stores over vc*9 float4s ========
    {
        const int nT4 = vc * 9;
        float4u* dT4 = (float4u*)(oT + (size_t)blockBase * 36);
#pragma unroll 2
        for (int rr = 0; rr < 9; ++rr) {
            const int Q = tid + (rr << 8);
            if (Q >= nT4) break;
            const unsigned c   = (unsigned)Q / 9u;
            const unsigned rem = (unsigned)Q - c * 9u;      // which float4 of 36 dwords
            const unsigned ins = __float_as_uint(lds[c * LSTR + 8]);
            const int cell19 = (blockBase + (int)c) * 19;
            float4u o;
#pragma unroll
            for (int u = 0; u < 4; ++u) {
                const unsigned P  = 4u * rem + (unsigned)u;  // 0..35
                const unsigned ti = P / 6u;
                const unsigned v  = P - ti * 6u;
                const unsigned tc = (unsigned)(TETP >> (6u * ti)) & 63u;
                const unsigned c1 = tc & 7u, c2 = tc >> 3;
                const unsigned cse = (ins & 1u)
                                   | (((ins >> c1) & 1u) << 1)
                                   | (((ins >> c2) & 1u) << 2)
                                   | (((ins >> 7) & 1u) << 3);
                const unsigned m  = MTP[cse];
                const unsigned tp = T2CPc[ti];
                const unsigned lt = (m >> (4u * v)) & 0xFu;
                const unsigned lc = (lt == 15u) ? 0u : lt;
                const unsigned ce = (tp >> (5u * lc)) & 31u;
                o[u] = (lt == 15u) ? -1.0f : (float)(cell19 + (int)ce);
            }
            dT4[Q] = o;
        }
    }
}

extern "C" void kernel_launch(void* const* d_in, const int* in_sizes, int n_in,
                              void* d_out, int out_size, void* d_ws, size_t ws_size,
                              hipStream_t stream) {
    const float* sdf  = (const float*)d_in[0];
    const float* feat = (const float*)d_in[1];
    float* out = (float*)d_out;
    float* oV = out;
    float* oF = oV + (size_t)NCELL * NE * 3;
    float* oT = oF + (size_t)NCELL * NE * NF;
    int blocks = (NCELL + 255) / 256;
    diffmc_kernel<<<blocks, 256, 0, stream>>>(sdf, feat, oV, oF, oT);
}